// Round 1
// baseline (7643.873 us; speedup 1.0000x reference)
//
#include <hip/hip_runtime.h>
#include <stdint.h>

#define NN 50000
#define NE 800000

// ---- monotone float<->uint32 key mapping for atomicMax-based segment max ----
static __device__ __forceinline__ uint32_t f2key(float f) {
    uint32_t b = __float_as_uint(f);
    return (b & 0x80000000u) ? ~b : (b | 0x80000000u);
}
static __device__ __forceinline__ float key2f(uint32_t k) {
    uint32_t b = (k & 0x80000000u) ? (k ^ 0x80000000u) : ~k;
    return __uint_as_float(b);
}
#define KEY_INIT 0x007FFFFFu   // f2key(-inf); any finite float maps above this

// ---------------------------------------------------------------------------
// Kernel A: node transform.  u = y @ (W1a - W1b) + b1 ; v = y @ W1b
// Input y is either raw x (layer 0) or previous layer's keys buffer
// (unmap + add prev b2 + relu fused into the LDS staging).
// Block = COUT threads, 32 nodes per block.
// ---------------------------------------------------------------------------
template<int CIN, int COUT, bool FROM_KEYS>
__global__ void node_transform(const float* __restrict__ xin,
                               const uint32_t* __restrict__ kin,
                               const float* __restrict__ b2p,
                               const float* __restrict__ W1,
                               const float* __restrict__ b1,
                               float* __restrict__ U,
                               float* __restrict__ Vv)
{
    __shared__ float ylds[32][CIN];
    const int nbase = blockIdx.x * 32;
    const int tid = threadIdx.x;

    for (int idx = tid; idx < 32 * CIN; idx += COUT) {
        int nn = idx / CIN, k = idx - nn * CIN;
        int n = nbase + nn;
        float val = 0.f;
        if (n < NN) {
            if (FROM_KEYS) {
                uint32_t kk = kin[(size_t)n * CIN + k];
                val = (kk == KEY_INIT) ? 0.f : fmaxf(key2f(kk) + b2p[k], 0.f);
            } else {
                val = xin[(size_t)n * CIN + k];
            }
        }
        ylds[nn][k] = val;
    }
    __syncthreads();

    const int j = tid;
    float ua[32], va[32];
    #pragma unroll
    for (int t = 0; t < 32; ++t) { ua[t] = 0.f; va[t] = 0.f; }

    for (int k4 = 0; k4 < CIN / 4; ++k4) {
        float wd[4], wb[4];
        #pragma unroll
        for (int i = 0; i < 4; ++i) {
            float a = W1[(size_t)(k4 * 4 + i) * COUT + j];
            float b = W1[(size_t)(CIN + k4 * 4 + i) * COUT + j];
            wb[i] = b;
            wd[i] = a - b;
        }
        #pragma unroll
        for (int t = 0; t < 32; ++t) {
            const float4 y4 = *reinterpret_cast<const float4*>(&ylds[t][k4 * 4]);
            ua[t] = fmaf(y4.x, wd[0], ua[t]);
            ua[t] = fmaf(y4.y, wd[1], ua[t]);
            ua[t] = fmaf(y4.z, wd[2], ua[t]);
            ua[t] = fmaf(y4.w, wd[3], ua[t]);
            va[t] = fmaf(y4.x, wb[0], va[t]);
            va[t] = fmaf(y4.y, wb[1], va[t]);
            va[t] = fmaf(y4.z, wb[2], va[t]);
            va[t] = fmaf(y4.w, wb[3], va[t]);
        }
    }

    const float bj = b1[j];
    for (int t = 0; t < 32; ++t) {
        int n = nbase + t;
        if (n < NN) {
            U [(size_t)n * COUT + j] = ua[t] + bj;
            Vv[(size_t)n * COUT + j] = va[t];
        }
    }
}

// ---------------------------------------------------------------------------
// Kernel B: per-edge MLP second matmul + scatter-max.
//   t = relu(u[dst] + v[src]);  h = t @ W2;  keys[dst] = max(keys[dst], h)
// (b2 is added later, at unmap time: max(h)+b2 == max(h+b2); empty -> 0.)
// Block = 256 (4 waves). Each wave owns 16 edges per block-tile of 64 edges.
// Register blocking: lane = (4 edges) x (COUT/16 cols), 32 FMA per k for C=128.
// ---------------------------------------------------------------------------
template<int COUT>
__global__ void __launch_bounds__(256, 1) edge_mlp(
    const float* __restrict__ U, const float* __restrict__ Vv,
    const int* __restrict__ src, const int* __restrict__ dst,
    const float* __restrict__ W2, uint32_t* __restrict__ keys)
{
    constexpr int TP = COUT + 4;   // padded t row stride (keeps 16B align, breaks bank stride)
    constexpr int GP = COUT / 4;   // float4 groups per row
    constexpr int JT = COUT / 16;  // cols per lane (8 for C=128, 4 for C=64)

    __shared__ float w2s[COUT * COUT];
    __shared__ float tl[4][16 * TP];

    const int tid = threadIdx.x;
    {
        const float4* s = reinterpret_cast<const float4*>(W2);
        float4* d4 = reinterpret_cast<float4*>(w2s);
        for (int i = tid; i < COUT * COUT / 4; i += 256) d4[i] = s[i];
    }
    __syncthreads();

    const int wave = tid >> 6, lane = tid & 63;
    float* tw = tl[wave];
    const int e_lo = (lane >> 4) << 2;        // {0,4,8,12}
    const int j0 = (lane & 15) * JT;

    const int NBT = NE / 64;                  // 12500 block-tiles of 64 edges
    for (int bt = blockIdx.x; bt < NBT; bt += gridDim.x) {
        const int ebase = bt * 64 + wave * 16;

        // ---- build t tile (16 edges x COUT) into per-wave LDS ----
        #pragma unroll
        for (int r = 0; r < 16 * GP / 64; ++r) {
            int item = r * 64 + lane;
            int e = item / GP, g = item - e * GP;
            int ed = dst[ebase + e], es = src[ebase + e];
            float4 u4 = *reinterpret_cast<const float4*>(&U [(size_t)ed * COUT + g * 4]);
            float4 v4 = *reinterpret_cast<const float4*>(&Vv[(size_t)es * COUT + g * 4]);
            float4 t4;
            t4.x = fmaxf(u4.x + v4.x, 0.f);
            t4.y = fmaxf(u4.y + v4.y, 0.f);
            t4.z = fmaxf(u4.z + v4.z, 0.f);
            t4.w = fmaxf(u4.w + v4.w, 0.f);
            *reinterpret_cast<float4*>(&tw[e * TP + g * 4]) = t4;
        }
        __syncthreads();

        // ---- register-blocked GEMM: [16 x COUT] @ [COUT x COUT] ----
        float acc[4][JT];
        #pragma unroll
        for (int i = 0; i < 4; ++i)
            #pragma unroll
            for (int jj = 0; jj < JT; ++jj) acc[i][jj] = 0.f;

        #pragma unroll 4
        for (int k = 0; k < COUT; ++k) {
            float tv[4];
            #pragma unroll
            for (int i = 0; i < 4; ++i) tv[i] = tw[(e_lo + i) * TP + k];
            float wrow[JT];
            #pragma unroll
            for (int q = 0; q < JT / 4; ++q)
                *reinterpret_cast<float4*>(&wrow[q * 4]) =
                    *reinterpret_cast<const float4*>(&w2s[k * COUT + j0 + q * 4]);
            #pragma unroll
            for (int i = 0; i < 4; ++i)
                #pragma unroll
                for (int jj = 0; jj < JT; ++jj)
                    acc[i][jj] = fmaf(tv[i], wrow[jj], acc[i][jj]);
        }

        // ---- scatter-max epilogue (no LDS) ----
        #pragma unroll
        for (int i = 0; i < 4; ++i) {
            const int ed = dst[ebase + e_lo + i];
            uint32_t* kp = &keys[(size_t)ed * COUT + j0];
            #pragma unroll
            for (int jj = 0; jj < JT; ++jj)
                atomicMax(&kp[jj], f2key(acc[i][jj]));
        }
        __syncthreads();   // protect tw before next iteration's build
    }
}

__global__ void init_keys(uint32_t* __restrict__ keys, int count) {
    int i = blockIdx.x * 256 + threadIdx.x;
    if (i < count) keys[i] = KEY_INIT;
}

__global__ void finalize_out(const uint32_t* __restrict__ keys,
                             const float* __restrict__ b2,
                             float* __restrict__ out) {
    int i = blockIdx.x * 256 + threadIdx.x;
    if (i < NN * 128) {
        uint32_t k = keys[i];
        out[i] = (k == KEY_INIT) ? 0.f : key2f(k) + b2[i & 127];
    }
}

// ---------------------------------------------------------------------------
extern "C" void kernel_launch(void* const* d_in, const int* in_sizes, int n_in,
                              void* d_out, int out_size, void* d_ws, size_t ws_size,
                              hipStream_t stream)
{
    const float* x  = (const float*)d_in[0];
    const int*   ei = (const int*)d_in[1];
    const int* src = ei;           // edge_index[0]
    const int* dst = ei + NE;      // edge_index[1]

    const float *W1[4], *B1[4], *W2[4], *B2[4];
    for (int i = 0; i < 4; ++i) {
        W1[i] = (const float*)d_in[2 + 4 * i];
        B1[i] = (const float*)d_in[3 + 4 * i];
        W2[i] = (const float*)d_in[4 + 4 * i];
        B2[i] = (const float*)d_in[5 + 4 * i];
    }

    float* U = (float*)d_ws;
    float* V = U + (size_t)NN * 128;
    uint32_t* keys = (uint32_t*)(V + (size_t)NN * 128);
    float* out = (float*)d_out;

    const int nblkA = (NN + 31) / 32;   // 1563

    // ---- layer 0: 32 -> 64 ----
    hipLaunchKernelGGL((node_transform<32, 64, false>), dim3(nblkA), dim3(64), 0, stream,
                       x, nullptr, nullptr, W1[0], B1[0], U, V);
    hipLaunchKernelGGL(init_keys, dim3((NN * 64 + 255) / 256), dim3(256), 0, stream,
                       keys, NN * 64);
    hipLaunchKernelGGL((edge_mlp<64>), dim3(1024), dim3(256), 0, stream,
                       U, V, src, dst, W2[0], keys);

    // ---- layer 1: 64 -> 128 ----
    hipLaunchKernelGGL((node_transform<64, 128, true>), dim3(nblkA), dim3(128), 0, stream,
                       nullptr, keys, B2[0], W1[1], B1[1], U, V);
    hipLaunchKernelGGL(init_keys, dim3((NN * 128 + 255) / 256), dim3(256), 0, stream,
                       keys, NN * 128);
    hipLaunchKernelGGL((edge_mlp<128>), dim3(1024), dim3(256), 0, stream,
                       U, V, src, dst, W2[1], keys);

    // ---- layer 2: 128 -> 128 ----
    hipLaunchKernelGGL((node_transform<128, 128, true>), dim3(nblkA), dim3(128), 0, stream,
                       nullptr, keys, B2[1], W1[2], B1[2], U, V);
    hipLaunchKernelGGL(init_keys, dim3((NN * 128 + 255) / 256), dim3(256), 0, stream,
                       keys, NN * 128);
    hipLaunchKernelGGL((edge_mlp<128>), dim3(1024), dim3(256), 0, stream,
                       U, V, src, dst, W2[2], keys);

    // ---- layer 3: 128 -> 128 ----
    hipLaunchKernelGGL((node_transform<128, 128, true>), dim3(nblkA), dim3(128), 0, stream,
                       nullptr, keys, B2[2], W1[3], B1[3], U, V);
    hipLaunchKernelGGL(init_keys, dim3((NN * 128 + 255) / 256), dim3(256), 0, stream,
                       keys, NN * 128);
    hipLaunchKernelGGL((edge_mlp<128>), dim3(1024), dim3(256), 0, stream,
                       U, V, src, dst, W2[3], keys);

    // ---- finalize: unmap + add b2_3, empty segments -> 0, no relu ----
    hipLaunchKernelGGL(finalize_out, dim3((NN * 128 + 255) / 256), dim3(256), 0, stream,
                       keys, B2[3], out);
}

// Round 3
// 2677.765 us; speedup vs baseline: 2.8546x; 2.8546x over previous
//
#include <hip/hip_runtime.h>
#include <stdint.h>
#include <math.h>

#define NN 50000
#define NE 800000

// Wave-internal LDS producer->consumer fence (wave is lockstep; lgkmcnt(0)
// guarantees this wave's ds_writes are visible to its own ds_reads).
static __device__ __forceinline__ void wave_lds_fence() {
    asm volatile("s_waitcnt lgkmcnt(0)" ::: "memory");
}

// ---------------------------------------------------------------------------
// One-time CSR build: histogram -> exclusive scan -> scatter (src only).
// Order within a dst bucket is nondeterministic (atomicAdd) but consumed only
// by an exact max reduction -> output is deterministic.
// ---------------------------------------------------------------------------
__global__ void hist_k(const int* __restrict__ dst, int* __restrict__ hist) {
    int e = blockIdx.x * 256 + threadIdx.x;
    if (e < NE) atomicAdd(&hist[dst[e]], 1);
}

__global__ void scan_k(const int* __restrict__ hist, int* __restrict__ row_off) {
    __shared__ int lds[1024];
    const int tid = threadIdx.x;
    int carry = 0;
    for (int base = 0; base < NN; base += 1024) {
        int i = base + tid;
        int v = (i < NN) ? hist[i] : 0;
        lds[tid] = v;
        __syncthreads();
        #pragma unroll
        for (int s = 1; s < 1024; s <<= 1) {
            int add = (tid >= s) ? lds[tid - s] : 0;
            __syncthreads();
            lds[tid] += add;
            __syncthreads();
        }
        int incl = lds[tid];
        if (i < NN) row_off[i] = carry + incl - v;   // exclusive
        carry += lds[1023];
        __syncthreads();
    }
    if (tid == 0) row_off[NN] = carry;               // == NE
}

__global__ void copy_k(const int* __restrict__ a, int* __restrict__ b, int n) {
    int i = blockIdx.x * 256 + threadIdx.x;
    if (i < n) b[i] = a[i];
}

__global__ void scatter_k(const int* __restrict__ src, const int* __restrict__ dst,
                          int* __restrict__ cnt, int* __restrict__ s_src) {
    int e = blockIdx.x * 256 + threadIdx.x;
    if (e < NE) {
        int d = dst[e];
        int p = atomicAdd(&cnt[d], 1);
        s_src[p] = src[e];
    }
}

// ---------------------------------------------------------------------------
// Node transform: u = y @ (W1a - W1b) + b1 ; v = y @ W1b
// y = x (FIRST) or relu(agg + b2_prev)  [agg==-inf sentinel -> relu -> 0].
// ---------------------------------------------------------------------------
template<int CIN, int COUT, bool FIRST>
__global__ void node_transform(const float* __restrict__ xin,
                               const float* __restrict__ ain,
                               const float* __restrict__ b2p,
                               const float* __restrict__ W1,
                               const float* __restrict__ b1,
                               float* __restrict__ U,
                               float* __restrict__ Vv)
{
    __shared__ float ylds[32][CIN];
    const int nbase = blockIdx.x * 32;
    const int tid = threadIdx.x;

    for (int idx = tid; idx < 32 * CIN; idx += COUT) {
        int nn = idx / CIN, k = idx - nn * CIN;
        int n = nbase + nn;
        float val = 0.f;
        if (n < NN) {
            if (FIRST) {
                val = xin[(size_t)n * CIN + k];
            } else {
                float a = ain[(size_t)n * CIN + k];
                val = fmaxf(a + b2p[k], 0.f);   // -inf sentinel -> 0
            }
        }
        ylds[nn][k] = val;
    }
    __syncthreads();

    const int j = tid;
    float ua[32], va[32];
    #pragma unroll
    for (int t = 0; t < 32; ++t) { ua[t] = 0.f; va[t] = 0.f; }

    for (int k4 = 0; k4 < CIN / 4; ++k4) {
        float wd[4], wb[4];
        #pragma unroll
        for (int i = 0; i < 4; ++i) {
            float a = W1[(size_t)(k4 * 4 + i) * COUT + j];
            float b = W1[(size_t)(CIN + k4 * 4 + i) * COUT + j];
            wb[i] = b;
            wd[i] = a - b;
        }
        #pragma unroll
        for (int t = 0; t < 32; ++t) {
            const float4 y4 = *reinterpret_cast<const float4*>(&ylds[t][k4 * 4]);
            ua[t] = fmaf(y4.x, wd[0], ua[t]);
            ua[t] = fmaf(y4.y, wd[1], ua[t]);
            ua[t] = fmaf(y4.z, wd[2], ua[t]);
            ua[t] = fmaf(y4.w, wd[3], ua[t]);
            va[t] = fmaf(y4.x, wb[0], va[t]);
            va[t] = fmaf(y4.y, wb[1], va[t]);
            va[t] = fmaf(y4.z, wb[2], va[t]);
            va[t] = fmaf(y4.w, wb[3], va[t]);
        }
    }

    const float bj = b1[j];
    for (int t = 0; t < 32; ++t) {
        int n = nbase + t;
        if (n < NN) {
            U [(size_t)n * COUT + j] = ua[t] + bj;
            Vv[(size_t)n * COUT + j] = va[t];
        }
    }
}

// ---------------------------------------------------------------------------
// Per-node edge MLP + max aggregation. One wave per dst node, CSR edges.
//   per 16-edge pass: t = relu(u[n] + v[src]) -> LDS (XOR-swizzled),
//   [16 x COUT] @ [COUT x COUT] reg-blocked GEMM, masked in-reg max,
//   shfl_xor reduce across edge groups, direct store (NO atomics).
// Block = 512 (8 waves = 8 nodes). LDS = W2 + 8 per-wave t tiles.
// ---------------------------------------------------------------------------
// XOR swizzle of the float4-group index so the 4 edge-groups' tv reads hit
// disjoint bank quads (e*COUT*4B contributes 0 to bank for COUT=64/128).
static __device__ __forceinline__ int tswz(int e, int k4) {
    return k4 ^ ((e >> 2) ^ ((e & 1) << 2));
}

template<int COUT>
__global__ void __launch_bounds__(512, 2) edge_node_k(
    const float* __restrict__ U, const float* __restrict__ Vv,
    const int* __restrict__ s_src, const int* __restrict__ row_off,
    const float* __restrict__ W2, float* __restrict__ agg)
{
    constexpr int GP = COUT / 4;
    constexpr int JT = COUT / 16;

    __shared__ float w2s[COUT * COUT];
    __shared__ float tl[8][16 * COUT];

    const int tid = threadIdx.x;
    {
        const float4* s = reinterpret_cast<const float4*>(W2);
        float4* d4 = reinterpret_cast<float4*>(w2s);
        for (int i = tid; i < COUT * COUT / 4; i += 512) d4[i] = s[i];
    }
    __syncthreads();   // block-wide, uniform; no block syncs after this

    const int wave = tid >> 6, lane = tid & 63;
    float* tw = tl[wave];
    const int g = lane >> 4;          // edge group 0..3
    const int e_lo = g * 4;
    const int c = lane & 15;          // col group
    const int j0 = c * JT;

    const int n = blockIdx.x * 8 + wave;      // grid sized exactly NN/8
    const int off0 = row_off[n];
    const int deg  = row_off[n + 1] - off0;

    float nmax[JT];
    #pragma unroll
    for (int jj = 0; jj < JT; ++jj) nmax[jj] = -INFINITY;

    for (int pb = 0; pb < deg; pb += 16) {
        // ---- build t tile (16 edges x COUT), zero-padded past deg ----
        #pragma unroll
        for (int r = 0; r < 16 * GP / 64; ++r) {
            int item = r * 64 + lane;
            int e = item / GP, grp = item - e * GP;
            float4 t4 = {0.f, 0.f, 0.f, 0.f};
            int ge = pb + e;
            if (ge < deg) {
                int sv = s_src[off0 + ge];
                float4 u4 = *reinterpret_cast<const float4*>(&U [(size_t)n  * COUT + grp * 4]);
                float4 v4 = *reinterpret_cast<const float4*>(&Vv[(size_t)sv * COUT + grp * 4]);
                t4.x = fmaxf(u4.x + v4.x, 0.f);
                t4.y = fmaxf(u4.y + v4.y, 0.f);
                t4.z = fmaxf(u4.z + v4.z, 0.f);
                t4.w = fmaxf(u4.w + v4.w, 0.f);
            }
            *reinterpret_cast<float4*>(&tw[e * COUT + tswz(e, grp) * 4]) = t4;
        }
        wave_lds_fence();

        // ---- reg-blocked GEMM, k chunked by 4 (b128 tv reads) ----
        float acc[4][JT];
        #pragma unroll
        for (int i = 0; i < 4; ++i)
            #pragma unroll
            for (int jj = 0; jj < JT; ++jj) acc[i][jj] = 0.f;

        #pragma unroll 2
        for (int k4 = 0; k4 < GP; ++k4) {
            float4 tv[4];
            #pragma unroll
            for (int i = 0; i < 4; ++i)
                tv[i] = *reinterpret_cast<const float4*>(
                    &tw[(e_lo + i) * COUT + tswz(e_lo + i, k4) * 4]);
            #pragma unroll
            for (int kk = 0; kk < 4; ++kk) {
                float wr[JT];
                #pragma unroll
                for (int q = 0; q < JT / 4; ++q)
                    *reinterpret_cast<float4*>(&wr[q * 4]) =
                        *reinterpret_cast<const float4*>(
                            &w2s[(size_t)(k4 * 4 + kk) * COUT + j0 + q * 4]);
                #pragma unroll
                for (int i = 0; i < 4; ++i) {
                    float tvi = (kk == 0) ? tv[i].x : (kk == 1) ? tv[i].y
                              : (kk == 2) ? tv[i].z : tv[i].w;
                    #pragma unroll
                    for (int jj = 0; jj < JT; ++jj)
                        acc[i][jj] = fmaf(tvi, wr[jj], acc[i][jj]);
                }
            }
        }
        wave_lds_fence();   // GEMM reads done before next pass overwrites tw

        // ---- masked merge (pad rows excluded) + cross-group reduce ----
        float r8[JT];
        #pragma unroll
        for (int jj = 0; jj < JT; ++jj) r8[jj] = -INFINITY;
        #pragma unroll
        for (int i = 0; i < 4; ++i) {
            if (pb + e_lo + i < deg) {
                #pragma unroll
                for (int jj = 0; jj < JT; ++jj)
                    r8[jj] = fmaxf(r8[jj], acc[i][jj]);
            }
        }
        #pragma unroll
        for (int jj = 0; jj < JT; ++jj) {
            r8[jj] = fmaxf(r8[jj], __shfl_xor(r8[jj], 16, 64));
            r8[jj] = fmaxf(r8[jj], __shfl_xor(r8[jj], 32, 64));
            nmax[jj] = fmaxf(nmax[jj], r8[jj]);
        }
    }

    // ---- direct store (group 0 lanes cover all COUT cols). deg==0 -> -inf.
    if (g == 0) {
        #pragma unroll
        for (int q = 0; q < JT / 4; ++q) {
            float4 o;
            o.x = nmax[q * 4 + 0];
            o.y = nmax[q * 4 + 1];
            o.z = nmax[q * 4 + 2];
            o.w = nmax[q * 4 + 3];
            *reinterpret_cast<float4*>(&agg[(size_t)n * COUT + j0 + q * 4]) = o;
        }
    }
}

__global__ void finalize_k(const float* __restrict__ agg,
                           const float* __restrict__ b2,
                           float* __restrict__ out) {
    int i = blockIdx.x * 256 + threadIdx.x;
    if (i < NN * 128) {
        float a = agg[i];
        out[i] = (a == -INFINITY) ? 0.f : a + b2[i & 127];
    }
}

// ---------------------------------------------------------------------------
extern "C" void kernel_launch(void* const* d_in, const int* in_sizes, int n_in,
                              void* d_out, int out_size, void* d_ws, size_t ws_size,
                              hipStream_t stream)
{
    const float* x  = (const float*)d_in[0];
    const int*   ei = (const int*)d_in[1];
    const int* src = ei;          // edge_index[0]
    const int* dst = ei + NE;     // edge_index[1]

    const float *W1[4], *B1[4], *W2[4], *B2[4];
    for (int i = 0; i < 4; ++i) {
        W1[i] = (const float*)d_in[2 + 4 * i];
        B1[i] = (const float*)d_in[3 + 4 * i];
        W2[i] = (const float*)d_in[4 + 4 * i];
        B2[i] = (const float*)d_in[5 + 4 * i];
    }

    float* U   = (float*)d_ws;
    float* V   = U   + (size_t)NN * 128;
    float* agg = V   + (size_t)NN * 128;
    int* row_off = (int*)(agg + (size_t)NN * 128);
    int* cnt     = row_off + (NN + 1);
    int* s_src   = cnt + NN;

    float* out = (float*)d_out;

    // ---- one-time CSR build (edges shared by all 4 layers) ----
    (void)hipMemsetAsync(cnt, 0, (size_t)NN * sizeof(int), stream);
    hipLaunchKernelGGL(hist_k, dim3((NE + 255) / 256), dim3(256), 0, stream, dst, cnt);
    hipLaunchKernelGGL(scan_k, dim3(1), dim3(1024), 0, stream, cnt, row_off);
    hipLaunchKernelGGL(copy_k, dim3((NN + 255) / 256), dim3(256), 0, stream, row_off, cnt, NN);
    hipLaunchKernelGGL(scatter_k, dim3((NE + 255) / 256), dim3(256), 0, stream, src, dst, cnt, s_src);

    const int nblkA = (NN + 31) / 32;      // node_transform blocks
    const int nblkE = NN / 8;              // 6250, exactly 8 nodes/block

    // ---- layer 0: 32 -> 64 ----
    hipLaunchKernelGGL((node_transform<32, 64, true>), dim3(nblkA), dim3(64), 0, stream,
                       x, nullptr, nullptr, W1[0], B1[0], U, V);
    hipLaunchKernelGGL((edge_node_k<64>), dim3(nblkE), dim3(512), 0, stream,
                       U, V, s_src, row_off, W2[0], agg);

    // ---- layer 1: 64 -> 128 ----
    hipLaunchKernelGGL((node_transform<64, 128, false>), dim3(nblkA), dim3(128), 0, stream,
                       nullptr, agg, B2[0], W1[1], B1[1], U, V);
    hipLaunchKernelGGL((edge_node_k<128>), dim3(nblkE), dim3(512), 0, stream,
                       U, V, s_src, row_off, W2[1], agg);

    // ---- layer 2: 128 -> 128 ----
    hipLaunchKernelGGL((node_transform<128, 128, false>), dim3(nblkA), dim3(128), 0, stream,
                       nullptr, agg, B2[1], W1[2], B1[2], U, V);
    hipLaunchKernelGGL((edge_node_k<128>), dim3(nblkE), dim3(512), 0, stream,
                       U, V, s_src, row_off, W2[2], agg);

    // ---- layer 3: 128 -> 128 ----
    hipLaunchKernelGGL((node_transform<128, 128, false>), dim3(nblkA), dim3(128), 0, stream,
                       nullptr, agg, B2[2], W1[3], B1[3], U, V);
    hipLaunchKernelGGL((edge_node_k<128>), dim3(nblkE), dim3(512), 0, stream,
                       U, V, s_src, row_off, W2[3], agg);

    // ---- finalize: +b2_3, empty -> 0, no relu ----
    hipLaunchKernelGGL(finalize_k, dim3((NN * 128 + 255) / 256), dim3(256), 0, stream,
                       agg, B2[3], out);
}